// Round 6
// baseline (124.122 us; speedup 1.0000x reference)
//
#include <hip/hip_runtime.h>

// StructureTensorEffect: B=4, C=3, H=W=1024, fp32.
// Round 12: shrink the LDS pipe. The 42-46us plateau (R3/R7/R8/R9/R11
// across wildly different structures) matches a SUM of pipes: LDS reads
// ~15-17us (5 scalar ds_read per window-row x channel x thread -- the
// biggest pipe, underestimated every round), VALU ~10us, HBM writes 8us
// (+ reads ~0, L3-absorbed: warm==cold measured R10). Overlap-reshuffles
// failed 4 rounds; so cut the biggest term. This round: full-width bands,
// 2 adjacent columns per thread. Each (window-row, channel) loads 2IP+4
// CONSECUTIVE dwords shared by both columns (adjacent lanes stride-2
// dwords -> compiler merges to ds_read2_b32/b64, conflict-free): ~3
// merged reads per 2 cols vs 10 scalar -> LDS pipe ~17 -> ~4us. Tile =
// 512 cols x 8 rows, per-channel staging (29KB LDS -> 5 blk/CU, 20
// waves). Stores: direct float2 (512B/wave contiguous), no LDS bounce.
// Staging: global_load_lds 16B/lane (LDS linear in group idx; per-lane
// clamped GLOBAL addr does border replication), per channel phase.
// Borders: R4-proven scheme (store mask + border slice, dispatched
// first, 8 blocks/batch = 5 iters/thread).

#define W_ 1024
#define H_ 1024
#define PLANE (1 << 20)
#define TCOLS 512
#define TROWS 8
#define ROWS 8
#define LSTRIDE 520    // staged cols: x0-4 .. x0+515 (130 float4 groups)
#define GPR 130        // float4 groups per staged row

__device__ __forceinline__ float lerp1(float a, float b, float f) {
    return fmaf(f, b - a, a);
}

// async 16B global->LDS copy (gfx950). Dest must be linear in lane order.
__device__ __forceinline__ void async_copy16(const float* g, float* s) {
    __builtin_amdgcn_global_load_lds(
        (const __attribute__((address_space(1))) unsigned int*)g,
        (__attribute__((address_space(3))) unsigned int*)s,
        16, 0, 0);
}

// Exact per-pixel reference path (any sigma, any border) — verified R1-R11.
__device__ void slow_pixel(const float* __restrict__ Xb, float* __restrict__ Ob,
                           float sg, int xi, int y)
{
    float imf = floorf(-sg), ipf = floorf(sg);
    float fm  = -sg - imf;
    float fp  =  sg - ipf;
    int   im  = (int)imf, ip = (int)ipf;

    int cm0 = min(max(xi + im, 0), W_ - 1), cm1 = min(cm0 + 1, W_ - 1);
    int cp0 = min(max(xi + ip, 0), W_ - 1), cp1 = min(cp0 + 1, W_ - 1);
    int rm0 = min(max(y + im, 0), H_ - 1),  rm1 = min(rm0 + 1, H_ - 1);
    int rp0 = min(max(y + ip, 0), H_ - 1),  rp1 = min(rp0 + 1, H_ - 1);

    int o_rm0 = rm0 << 10, o_rm1 = rm1 << 10;
    int o_rp0 = rp0 << 10, o_rp1 = rp1 << 10;
    int o_r0  = y   << 10;

    float oxx = 0.f, oyy = 0.f, oxy = 0.f;

    #pragma unroll
    for (int c = 0; c < 3; ++c) {
        const float* base = Xb + ((size_t)c << 20);

        float hm_m0 = lerp1(base[o_rm0 + cm0], base[o_rm0 + cm1], fm);
        float hm_m1 = lerp1(base[o_rm1 + cm0], base[o_rm1 + cm1], fm);
        float hm_0  = lerp1(base[o_r0  + cm0], base[o_r0  + cm1], fm);
        float hm_p0 = lerp1(base[o_rp0 + cm0], base[o_rp0 + cm1], fm);
        float hm_p1 = lerp1(base[o_rp1 + cm0], base[o_rp1 + cm1], fm);
        float hp_m0 = lerp1(base[o_rm0 + cp0], base[o_rm0 + cp1], fp);
        float hp_m1 = lerp1(base[o_rm1 + cp0], base[o_rm1 + cp1], fp);
        float hp_0  = lerp1(base[o_r0  + cp0], base[o_r0  + cp1], fp);
        float hp_p0 = lerp1(base[o_rp0 + cp0], base[o_rp0 + cp1], fp);
        float hp_p1 = lerp1(base[o_rp1 + cp0], base[o_rp1 + cp1], fp);
        float h0_m0 = base[o_rm0 + xi], h0_m1 = base[o_rm1 + xi];
        float h0_p0 = base[o_rp0 + xi], h0_p1 = base[o_rp1 + xi];

        float t0 = lerp1(hm_m0, hm_m1, fm);
        float t1 = hm_0;
        float t2 = lerp1(hm_p0, hm_p1, fp);
        float t3 = lerp1(h0_m0, h0_m1, fm);
        float t4 = lerp1(h0_p0, h0_p1, fp);
        float t5 = lerp1(hp_m0, hp_m1, fm);
        float t6 = hp_0;
        float t7 = lerp1(hp_p0, hp_p1, fp);

        float su = 0.25f * (t5 + t7 - t0 - t2) + 0.5f * (t6 - t1);
        float sv = 0.25f * (t2 + t7 - t0 - t5) + 0.5f * (t4 - t3);

        float l2 = (c == 0) ? 10000.f : 1.f;
        oxx = fmaf(l2 * su, su, oxx);
        oyy = fmaf(l2 * sv, sv, oyy);
        oxy = fmaf(l2 * su, sv, oxy);
    }

    int pix = (y << 10) | xi;
    Ob[pix]             = oxx;
    Ob[PLANE + pix]     = oyy;
    Ob[2 * PLANE + pix] = oxy;
}

template<int N>
__device__ __forceinline__ void acc(float (&arr)[N], int k, float val) {
    if (k >= 0 && k < N) arr[k] += val;   // k constant after unroll
}

// Fast tile: block covers cols x0..x0+511 (2 adjacent cols/thread), rows
// y0..y0+7. Per channel: stage clamped window (rows y0-IP-1..y0+8+IP,
// cols x0-4..x0+515) -> barrier -> streaming accumulate (2IP+4
// consecutive dwords per window row, shared across the thread's 2 cols)
// -> barrier. Store mask (x>IP && x<1023-IP && y>IP) excludes clamp-
// wrong px; those are covered by the border slice.
template<int IP>
__device__ void fast_tile(const float* __restrict__ Xb, float* __restrict__ Ob,
                          float fp, float fm, int x0, int y0,
                          int tx, float* smem)
{
    constexpr int LROWS  = TROWS + 2 * IP + 2;   // staged rows per channel
    constexpr int RW     = ROWS + 2 * IP + 2;    // window rows per thread
    constexpr int NG     = LROWS * GPR;          // float4 groups per channel
    constexpr int FULLIT = NG / 256;             // guard-free iterations
    constexpr int NT     = 2 * IP + 4;           // taps per window row

    float oxx[2][ROWS], oyy[2][ROWS], oxy[2][ROWS];
    #pragma unroll
    for (int l = 0; l < 2; ++l)
        #pragma unroll
        for (int k = 0; k < ROWS; ++k) { oxx[l][k] = 0.f; oyy[l][k] = 0.f; oxy[l][k] = 0.f; }

    // thread's LDS tap base: local col of global col g is g-(x0-4);
    // col0 = x0+2tx -> local 2tx+4; leftmost tap at col0-IP-1.
    const float* sp = smem + 2 * tx + 4 - IP - 1;

    #pragma unroll
    for (int c = 0; c < 3; ++c) {
        const float* Xc = Xb + ((size_t)c << 20);

        // ---- stage this channel's window (direct-to-LDS, linear in g) ----
        #pragma unroll
        for (int it = 0; it < FULLIT; ++it) {
            int g   = it * 256 + tx;
            int row = g / GPR;
            int grp = g - row * GPR;
            int gr  = min(max(y0 - IP - 1 + row, 0), H_ - 1);
            int gc  = min(max(x0 - 4 + grp * 4, 0), W_ - 4);
            async_copy16(Xc + (gr << 10) + gc, smem + g * 4);
        }
        {
            int g = FULLIT * 256 + tx;
            if (g < NG) {                  // single guarded tail copy
                int row = g / GPR;
                int grp = g - row * GPR;
                int gr  = min(max(y0 - IP - 1 + row, 0), H_ - 1);
                int gc  = min(max(x0 - 4 + grp * 4, 0), W_ - 4);
                async_copy16(Xc + (gr << 10) + gc, smem + g * 4);
            }
        }
        __syncthreads();   // vmcnt(0) drain + barrier

        // ---- streaming accumulate, 2 columns per thread ----
        float su[2][ROWS], sv[2][ROWS];
        #pragma unroll
        for (int l = 0; l < 2; ++l)
            #pragma unroll
            for (int k = 0; k < ROWS; ++k) { su[l][k] = 0.f; sv[l][k] = 0.f; }

        #pragma unroll
        for (int w = 0; w < RW; ++w) {
            float v[NT];
            #pragma unroll
            for (int j = 0; j < NT; ++j) v[j] = sp[w * LSTRIDE + j];

            #pragma unroll
            for (int l = 0; l < 2; ++l) {
                // taps for col l: a0=v[l], a1=v[l+1], cc=v[IP+1+l],
                // b0=v[2IP+1+l], b1=v[2IP+2+l]
                float hm = lerp1(v[l],            v[l + 1],        fm);
                float hp = lerp1(v[2*IP + 1 + l], v[2*IP + 2 + l], fp);
                float cc = v[IP + 1 + l];
                float q  = hp - hm;
                float A  = 0.25f * q;
                float hq = 0.5f  * q;
                float Bv = fmaf(0.25f, hm + hp, 0.5f * cc);
                float fpA = fp * A,  fmA = fm * A;
                float fpB = fp * Bv, fmB = fm * Bv;

                acc(su[l], w,              fpA);
                acc(su[l], w - 1,          fmA);
                acc(su[l], w - IP - 1,     hq);
                acc(su[l], w - 2*IP - 1,   fmA);
                acc(su[l], w - 2*IP - 2,   fpA);
                acc(sv[l], w,             -fpB);
                acc(sv[l], w - 1,         -fmB);
                acc(sv[l], w - 2*IP - 1,   fmB);
                acc(sv[l], w - 2*IP - 2,   fpB);
            }
        }

        float l2 = (c == 0) ? 10000.f : 1.f;
        #pragma unroll
        for (int l = 0; l < 2; ++l)
            #pragma unroll
            for (int k = 0; k < ROWS; ++k) {
                oxx[l][k] = fmaf(l2 * su[l][k], su[l][k], oxx[l][k]);
                oyy[l][k] = fmaf(l2 * sv[l][k], sv[l][k], oyy[l][k]);
                oxy[l][k] = fmaf(l2 * su[l][k], sv[l][k], oxy[l][k]);
            }

        __syncthreads();   // before restaging next channel
    }

    // ---- epilogue: direct float2 stores (512B contiguous per wave) ----
    int xg = x0 + 2 * tx;
    bool ok0 = (xg     > IP) && (xg     < W_ - 1 - IP);
    bool ok1 = (xg + 1 > IP) && (xg + 1 < W_ - 1 - IP);
    #pragma unroll
    for (int k = 0; k < ROWS; ++k) {
        int y = y0 + k;
        if (y <= IP) continue;
        int pix = (y << 10) + xg;
        float vals[3][2] = {{oxx[0][k], oxx[1][k]},
                            {oyy[0][k], oyy[1][k]},
                            {oxy[0][k], oxy[1][k]}};
        #pragma unroll
        for (int p = 0; p < 3; ++p) {
            float* dst = Ob + (size_t)p * PLANE + pix;
            if (ok0 && ok1) {
                *reinterpret_cast<float2*>(dst) =
                    make_float2(vals[p][0], vals[p][1]);
            } else {
                if (ok0) dst[0] = vals[p][0];
                if (ok1) dst[1] = vals[p][1];
            }
        }
    }
}

// block (256,1). grid = (2, 132, 4): y in {0..3} border slice (first,
// 8 blocks/batch), then 128 8-row bands.
__global__ __launch_bounds__(256) void st_kernel(
    const float* __restrict__ X, const float* __restrict__ S,
    float* __restrict__ O)
{
    int b  = blockIdx.z;
    const float* Xb = X + (size_t)b * 3 * PLANE;
    float*       Ob = O + (size_t)b * 3 * PLANE;
    float sg = S[b];

    int tx = threadIdx.x;

    if (blockIdx.y < 4) {
        // Border slice, dispatched first so its gather-heavy blocks
        // overlap under the fast-tile phase. x in {0,1,2,1021,1022,1023}
        // all y (6144 px) plus y in {0,1,2} all x (3072 px).
        // 8 blocks * 256 = 2048 threads -> 5 iters.
        int t = (blockIdx.y * gridDim.x + blockIdx.x) * 256 + tx;
        #pragma unroll
        for (int it = 0; it < 5; ++it) {
            int pidx = t + it * 2048;
            if (pidx < 6144) {
                int yy = pidx / 6;
                int cc = pidx - yy * 6;
                int xx = (cc < 3) ? cc : (W_ - 6 + cc);
                slow_pixel(Xb, Ob, sg, xx, yy);
            } else if (pidx < 9216) {
                int p2 = pidx - 6144;
                slow_pixel(Xb, Ob, sg, p2 & 1023, p2 >> 10);
            }
        }
        return;
    }

    int x0 = blockIdx.x * TCOLS;
    int y0 = (blockIdx.y - 4) * TROWS;

    int ipv = (int)floorf(sg);
    int imv = (int)floorf(-sg);
    bool sig_ok = (imv == -ipv - 1) && ipv >= 0 && ipv <= 2;  // block-uniform
    float fp = sg - (float)ipv;
    float fm = 1.0f - fp;

    // worst case IP=2: 14 rows x 520 cols x 4B = 29120 B -> 5 blk/CU
    __shared__ __align__(16) float smem[(TROWS + 6) * LSTRIDE];

    if (sig_ok) {
        switch (ipv) {
            case 0:  fast_tile<0>(Xb, Ob, fp, fm, x0, y0, tx, smem); break;
            case 1:  fast_tile<1>(Xb, Ob, fp, fm, x0, y0, tx, smem); break;
            default: fast_tile<2>(Xb, Ob, fp, fm, x0, y0, tx, smem); break;
        }
    } else {
        #pragma unroll
        for (int l = 0; l < 2; ++l)
            for (int k = 0; k < ROWS; ++k)
                slow_pixel(Xb, Ob, sg, x0 + 2 * tx + l, y0 + k);
    }
}

extern "C" void kernel_launch(void* const* d_in, const int* in_sizes, int n_in,
                              void* d_out, int out_size, void* d_ws, size_t ws_size,
                              hipStream_t stream) {
    const float* x     = (const float*)d_in[0];
    const float* sigma = (const float*)d_in[1];
    float* out = (float*)d_out;

    dim3 grid(W_ / TCOLS, H_ / TROWS + 4, 4), block(256, 1);
    hipLaunchKernelGGL(st_kernel, grid, block, 0, stream, x, sigma, out);
}

// Round 7
// 113.078 us; speedup vs baseline: 1.0977x; 1.0977x over previous
//
#include <hip/hip_runtime.h>

// StructureTensorEffect: B=4, C=3, H=W=1024, fp32.
// Round 13: persistent 4-tile blocks + counted-vmcnt double-buffered
// pipeline (T3/T4 idiom). Evidence: R7(3-phase)==R8(1-phase)==R9 at
// ~42-44us; R10 cold==warm; R11 wide stores ~same; R12 (2-col) regressed
// (VGPR 156, 491K bank conflicts). All pipe ceilings (LDS 14us/CU, VALU
// 9us, writes 8us) are << 42us, and occupancy 12->32 waves/CU changed
// nothing => model: blocks serially stall once per tile on the staged
// window (queue-limited, so 3 small waits == 1 big wait, explaining
// R7==R8), with ~2 live waves/SIMD not cross-hiding. None of R7-R12
// ever pipelined ACROSS tiles -- impossible with one-tile blocks. This
// round: persistent blocks own 4 consecutive y-bands; stage tile t+1
// into buffer B while computing tile t from buffer A. Counted
// s_waitcnt vmcnt(K) (NEVER 0) + raw s_barrier lets the next tile's
// global_load_lds stay in flight across the barrier. Staging made
// exec-uniform (tail clamped; junk lands in a 4KB LDS pad) so every
// wave issues exactly K=ITERS copies -> K is a compile-time constant.
// Geometry/compute/store = verified R8 body (64x32 tile, scatter
// stores). LDS 2 x 36928B -> 2 blocks/CU. Prologue amortized 4x.
// Borders: R4-proven scheme (store mask + border slice, dispatched first).

#define W_ 1024
#define H_ 1024
#define PLANE (1 << 20)
#define TCOLS 64
#define TROWS 32
#define ROWS 8
#define LSTRIDE 72     // staged cols: x0-4 .. x0+67 (18 float4 groups)
#define NTILES 4       // tiles (y-bands) per persistent block
#define BUFSZ 9232     // floats: 3*38*72 = 8208 (worst-case IP=2) + 1024 pad

__device__ __forceinline__ float lerp1(float a, float b, float f) {
    return fmaf(f, b - a, a);
}

// async 16B global->LDS copy (gfx950). Dest must be linear in lane order.
__device__ __forceinline__ void async_copy16(const float* g, float* s) {
    __builtin_amdgcn_global_load_lds(
        (const __attribute__((address_space(1))) unsigned int*)g,
        (__attribute__((address_space(3))) unsigned int*)s,
        16, 0, 0);
}

// Exact per-pixel reference path (any sigma, any border) — verified R1-R12.
__device__ void slow_pixel(const float* __restrict__ Xb, float* __restrict__ Ob,
                           float sg, int xi, int y)
{
    float imf = floorf(-sg), ipf = floorf(sg);
    float fm  = -sg - imf;
    float fp  =  sg - ipf;
    int   im  = (int)imf, ip = (int)ipf;

    int cm0 = min(max(xi + im, 0), W_ - 1), cm1 = min(cm0 + 1, W_ - 1);
    int cp0 = min(max(xi + ip, 0), W_ - 1), cp1 = min(cp0 + 1, W_ - 1);
    int rm0 = min(max(y + im, 0), H_ - 1),  rm1 = min(rm0 + 1, H_ - 1);
    int rp0 = min(max(y + ip, 0), H_ - 1),  rp1 = min(rp0 + 1, H_ - 1);

    int o_rm0 = rm0 << 10, o_rm1 = rm1 << 10;
    int o_rp0 = rp0 << 10, o_rp1 = rp1 << 10;
    int o_r0  = y   << 10;

    float oxx = 0.f, oyy = 0.f, oxy = 0.f;

    #pragma unroll
    for (int c = 0; c < 3; ++c) {
        const float* base = Xb + ((size_t)c << 20);

        float hm_m0 = lerp1(base[o_rm0 + cm0], base[o_rm0 + cm1], fm);
        float hm_m1 = lerp1(base[o_rm1 + cm0], base[o_rm1 + cm1], fm);
        float hm_0  = lerp1(base[o_r0  + cm0], base[o_r0  + cm1], fm);
        float hm_p0 = lerp1(base[o_rp0 + cm0], base[o_rp0 + cm1], fm);
        float hm_p1 = lerp1(base[o_rp1 + cm0], base[o_rp1 + cm1], fm);
        float hp_m0 = lerp1(base[o_rm0 + cp0], base[o_rm0 + cp1], fp);
        float hp_m1 = lerp1(base[o_rm1 + cp0], base[o_rm1 + cp1], fp);
        float hp_0  = lerp1(base[o_r0  + cp0], base[o_r0  + cp1], fp);
        float hp_p0 = lerp1(base[o_rp0 + cp0], base[o_rp0 + cp1], fp);
        float hp_p1 = lerp1(base[o_rp1 + cp0], base[o_rp1 + cp1], fp);
        float h0_m0 = base[o_rm0 + xi], h0_m1 = base[o_rm1 + xi];
        float h0_p0 = base[o_rp0 + xi], h0_p1 = base[o_rp1 + xi];

        float t0 = lerp1(hm_m0, hm_m1, fm);
        float t1 = hm_0;
        float t2 = lerp1(hm_p0, hm_p1, fp);
        float t3 = lerp1(h0_m0, h0_m1, fm);
        float t4 = lerp1(h0_p0, h0_p1, fp);
        float t5 = lerp1(hp_m0, hp_m1, fm);
        float t6 = hp_0;
        float t7 = lerp1(hp_p0, hp_p1, fp);

        float su = 0.25f * (t5 + t7 - t0 - t2) + 0.5f * (t6 - t1);
        float sv = 0.25f * (t2 + t7 - t0 - t5) + 0.5f * (t4 - t3);

        float l2 = (c == 0) ? 10000.f : 1.f;
        oxx = fmaf(l2 * su, su, oxx);
        oyy = fmaf(l2 * sv, sv, oyy);
        oxy = fmaf(l2 * su, sv, oxy);
    }

    int pix = (y << 10) | xi;
    Ob[pix]             = oxx;
    Ob[PLANE + pix]     = oyy;
    Ob[2 * PLANE + pix] = oxy;
}

template<int N>
__device__ __forceinline__ void acc(float (&arr)[N], int k, float val) {
    if (k >= 0 && k < N) arr[k] += val;   // k constant after unroll
}

// Persistent fast block: covers cols x0..x0+63, bands band0..band0+3
// (rows band*32..band*32+31). Double-buffered: stage tile t+1 while
// computing tile t; counted vmcnt keeps next-tile loads in flight
// across the raw barrier. Store mask (x>IP && x<1023-IP && y>IP)
// excludes clamp-wrong px; covered by the border slice.
template<int IP>
__device__ void fast_tiles(const float* __restrict__ Xb, float* __restrict__ Ob,
                           float fp, float fm, int x0, int band0,
                           int tx, int ty, int tid, float* smem)
{
    constexpr int LROWS = TROWS + 2 * IP + 2;   // staged rows per channel
    constexpr int RW    = ROWS + 2 * IP + 2;    // window rows per thread
    constexpr int NG    = 3 * LROWS * 18;       // float4 groups per tile
    constexpr int ITERS = (NG + 255) / 256;     // copies per thread (uniform)

    int x = x0 + tx;

    // Exec-uniform staging: every thread issues exactly ITERS copies.
    // Clamped tail groups re-load group NG-1; the HW writes LDS linearly
    // (wave-uniform base + lane*16), so tail junk lands at linear
    // positions NG..ITERS*256-1 -> inside the 1024-float pad. Each
    // wave's issue count is thus a compile-time vmcnt constant.
    auto stage = [&](float* buf, int y0) {
        #pragma unroll
        for (int it = 0; it < ITERS; ++it) {
            int g    = min(it * 256 + tid, NG - 1);
            int row  = g / 18;
            int grp  = g - row * 18;
            int c    = row / LROWS;
            int lrow = row - c * LROWS;
            int gr   = min(max(y0 - IP - 1 + lrow, 0), H_ - 1);
            int gc   = min(max(x0 - 4 + grp * 4, 0), W_ - 4);
            async_copy16(Xb + ((size_t)c << 20) + (gr << 10) + gc,
                         buf + g * 4);
        }
    };

    stage(smem,         (band0 + 0) * TROWS);   // tile 0 -> buf0
    stage(smem + BUFSZ, (band0 + 1) * TROWS);   // tile 1 -> buf1

    #pragma unroll
    for (int t = 0; t < NTILES; ++t) {
        float* buf = smem + (t & 1) * BUFSZ;
        int y0 = (band0 + t) * TROWS;

        // Counted wait: newest ITERS vmem ops = tile t+1's staging (or,
        // at t>=NTILES-2, >=15 unmasked stores from tile t-1, which
        // exceed ITERS). <=ITERS outstanding => tile t's loads landed.
        if constexpr (ITERS >= 9) asm volatile("s_waitcnt vmcnt(9)" ::: "memory");
        else                      asm volatile("s_waitcnt vmcnt(8)" ::: "memory");
        __builtin_amdgcn_s_barrier();   // all waves' tile-t loads landed

        float oxx[ROWS], oyy[ROWS], oxy[ROWS];
        #pragma unroll
        for (int k = 0; k < ROWS; ++k) { oxx[k] = 0.f; oyy[k] = 0.f; oxy[k] = 0.f; }

        // thread's LDS read base: window row w of channel c at LDS row
        // c*LROWS + ty*ROWS + w; col of global col g is g-(x0-4); a0 at
        // col x-IP-1 -> tx + 3 - IP.
        const float* spb = buf + (ty * ROWS) * LSTRIDE + tx + (3 - IP);

        #pragma unroll
        for (int c = 0; c < 3; ++c) {
            const float* sp = spb + c * (LROWS * LSTRIDE);

            float su[ROWS], sv[ROWS];
            #pragma unroll
            for (int k = 0; k < ROWS; ++k) { su[k] = 0.f; sv[k] = 0.f; }

            #pragma unroll
            for (int w = 0; w < RW; ++w) {
                float a0 = sp[w * LSTRIDE];
                float a1 = sp[w * LSTRIDE + 1];
                float cc = sp[w * LSTRIDE + IP + 1];
                float b0 = sp[w * LSTRIDE + 2 * IP + 1];
                float b1 = sp[w * LSTRIDE + 2 * IP + 2];
                float hm = lerp1(a0, a1, fm);
                float hp = lerp1(b0, b1, fp);
                float q  = hp - hm;
                float A  = 0.25f * q;
                float hq = 0.5f  * q;
                float Bv = fmaf(0.25f, hm + hp, 0.5f * cc);
                float fpA = fp * A,  fmA = fm * A;
                float fpB = fp * Bv, fmB = fm * Bv;

                acc(su, w,              fpA);
                acc(su, w - 1,          fmA);
                acc(su, w - IP - 1,     hq);
                acc(su, w - 2*IP - 1,   fmA);
                acc(su, w - 2*IP - 2,   fpA);
                acc(sv, w,             -fpB);
                acc(sv, w - 1,         -fmB);
                acc(sv, w - 2*IP - 1,   fmB);
                acc(sv, w - 2*IP - 2,   fpB);
            }

            float l2 = (c == 0) ? 10000.f : 1.f;
            #pragma unroll
            for (int k = 0; k < ROWS; ++k) {
                oxx[k] = fmaf(l2 * su[k], su[k], oxx[k]);
                oyy[k] = fmaf(l2 * sv[k], sv[k], oyy[k]);
                oxy[k] = fmaf(l2 * su[k], sv[k], oxy[k]);
            }
        }

        // scatter stores (verified R8/R9 pattern); >=15 per wave,
        // which keeps the t>=NTILES-2 vmcnt bound valid.
        bool okx = (x > IP) && (x < W_ - 1 - IP);
        int Y = y0 + ty * ROWS;
        #pragma unroll
        for (int k = 0; k < ROWS; ++k) {
            int y = Y + k;
            if (okx && y > IP) {
                int pix = (y << 10) | x;
                Ob[pix]             = oxx[k];
                Ob[PLANE + pix]     = oyy[k];
                Ob[2 * PLANE + pix] = oxy[k];
            }
        }

        asm volatile("s_waitcnt lgkmcnt(0)" ::: "memory");
        __builtin_amdgcn_s_barrier();   // all waves done reading buf
        if (t + 2 < NTILES)
            stage(buf, (band0 + t + 2) * TROWS);   // refill just-freed buf
    }
}

// block (64,4). grid = (16, 9, 4): y==0 border slice (first), then 8
// persistent groups of 4 bands each.
__global__ __launch_bounds__(256) void st_kernel(
    const float* __restrict__ X, const float* __restrict__ S,
    float* __restrict__ O)
{
    int b  = blockIdx.z;
    const float* Xb = X + (size_t)b * 3 * PLANE;
    float*       Ob = O + (size_t)b * 3 * PLANE;
    float sg = S[b];

    int tx = threadIdx.x, ty = threadIdx.y;
    int tid = ty * 64 + tx;

    if (blockIdx.y == 0) {
        // Border slice, dispatched first so its gather-heavy blocks
        // overlap under the fast phase. x in {0,1,2,1021,1022,1023} all
        // y (6144 px) plus y in {0,1,2} all x (3072 px). 16*256 = 4096
        // threads -> 3 iters.
        int t = blockIdx.x * 256 + tid;
        #pragma unroll
        for (int it = 0; it < 3; ++it) {
            int pidx = t + it * 4096;
            if (pidx < 6144) {
                int yy = pidx / 6;
                int cc = pidx - yy * 6;
                int xx = (cc < 3) ? cc : (W_ - 6 + cc);
                slow_pixel(Xb, Ob, sg, xx, yy);
            } else if (pidx < 9216) {
                int p2 = pidx - 6144;
                slow_pixel(Xb, Ob, sg, p2 & 1023, p2 >> 10);
            }
        }
        return;
    }

    int x0    = blockIdx.x * TCOLS;
    int band0 = (blockIdx.y - 1) * NTILES;

    int ipv = (int)floorf(sg);
    int imv = (int)floorf(-sg);
    bool sig_ok = (imv == -ipv - 1) && ipv >= 0 && ipv <= 2;  // block-uniform
    float fp = sg - (float)ipv;
    float fm = 1.0f - fp;

    // 2 buffers x (3ch x 38 rows x 72 cols + 1024-float staging pad)
    // = 73856 B -> 2 blocks/CU.
    __shared__ __align__(16) float smem[2 * BUFSZ];

    if (sig_ok) {
        switch (ipv) {
            case 0:  fast_tiles<0>(Xb, Ob, fp, fm, x0, band0, tx, ty, tid, smem); break;
            case 1:  fast_tiles<1>(Xb, Ob, fp, fm, x0, band0, tx, ty, tid, smem); break;
            default: fast_tiles<2>(Xb, Ob, fp, fm, x0, band0, tx, ty, tid, smem); break;
        }
    } else {
        for (int t = 0; t < NTILES; ++t)
            for (int k = 0; k < ROWS; ++k)
                slow_pixel(Xb, Ob, sg, x0 + tx,
                           (band0 + t) * TROWS + ty * ROWS + k);
    }
}

extern "C" void kernel_launch(void* const* d_in, const int* in_sizes, int n_in,
                              void* d_out, int out_size, void* d_ws, size_t ws_size,
                              hipStream_t stream) {
    const float* x     = (const float*)d_in[0];
    const float* sigma = (const float*)d_in[1];
    float* out = (float*)d_out;

    dim3 grid(W_ / TCOLS, H_ / TROWS / NTILES + 1, 4), block(64, 4);
    hipLaunchKernelGGL(st_kernel, grid, block, 0, stream, x, sigma, out);
}